// Round 1
// baseline (1553.101 us; speedup 1.0000x reference)
//
#include <hip/hip_runtime.h>
#include <stdint.h>

#define T_STEPS 100
#define D_IN 16
#define H_DIM 32
#define HD 50
#define KXH 48
#define EULER 10
#define STEPF 0.1f
#define DT_SCALERF (1.0f/24.0f)

typedef __attribute__((ext_vector_type(8))) short short8;
typedef __attribute__((ext_vector_type(4))) float float4v;

__device__ __forceinline__ float fast_tanh(float x) {
    // tanh(x) = 1 - 2/(e^{2x}+1); e^{2x} = exp2(x * 2*log2(e))
    float e = __builtin_amdgcn_exp2f(x * 2.8853900817779268f);
    return 1.0f - 2.0f * __builtin_amdgcn_rcpf(e + 1.0f);
}

__device__ __forceinline__ short f2bf(float f) {
    uint32_t u = __builtin_bit_cast(uint32_t, f);
    u += 0x7fffu + ((u >> 16) & 1u);   // RNE (no NaNs in this workload)
    return (short)(u >> 16);
}

__global__ __launch_bounds__(64) void latode_kernel(
    const float* __restrict__ dt, const float* __restrict__ x,
    const float* __restrict__ W1, const float* __restrict__ b1,
    const float* __restrict__ W2, const float* __restrict__ b2,
    const float* __restrict__ W3, const float* __restrict__ b3,
    const float* __restrict__ W4, const float* __restrict__ b4,
    float* __restrict__ out)
{
    const int lane = threadIdx.x;     // 0..63, one wave per block
    const int n16  = lane & 15;       // column (n) index in C-layout / row in A/B frags
    const int quad = lane >> 4;       // 0..3
    const int b0   = blockIdx.x * 16; // 16 batch rows per wave

    // LDS staging for C-layout -> A-fragment transforms (bf16)
    __shared__ short h_stage[16 * 40];   // [m][k0..31], row stride 40 (16B-aligned rows, depadded banks)
    __shared__ short a1_stage[16 * 72];  // [m][k0..63], row stride 72

    // ---------------- weight fragments (bf16, register-resident all kernel) ----------
    // B-frag layout: B[n = lane&15][k = quad*8+j]; weights are [out][in] = [n][k]. 
    // Concat order remapped to [h(32) | x(16) | pad(16)] so the x K-tile is static per t.
    short8 w1f[4][2];
#pragma unroll
    for (int nt = 0; nt < 4; ++nt) {
        int n = nt * 16 + n16;
#pragma unroll
        for (int kt = 0; kt < 2; ++kt)
#pragma unroll
            for (int j = 0; j < 8; ++j) {
                int kk = kt * 32 + quad * 8 + j;       // k' in [0,64)
                float w = 0.0f;
                if (n < HD) {
                    if (kk < 32)      w = W1[n * KXH + 16 + kk];      // h part
                    else if (kk < 48) w = W1[n * KXH + (kk - 32)];    // x part
                }
                w1f[nt][kt][j] = f2bf(w);
            }
    }
    short8 w2f[2][2];
#pragma unroll
    for (int nt = 0; nt < 2; ++nt) {
        int n = nt * 16 + n16;
#pragma unroll
        for (int kt = 0; kt < 2; ++kt)
#pragma unroll
            for (int j = 0; j < 8; ++j) {
                int kk = kt * 32 + quad * 8 + j;
                w2f[nt][kt][j] = f2bf(kk < HD ? W2[n * HD + kk] : 0.0f);
            }
    }
    short8 w3f[4];
#pragma unroll
    for (int nt = 0; nt < 4; ++nt) {
        int n = nt * 16 + n16;
#pragma unroll
        for (int j = 0; j < 8; ++j)
            w3f[nt][j] = f2bf(W3[n * H_DIM + quad * 8 + j]);
    }
    float b1f[4], b3f[4], w4f[4];
#pragma unroll
    for (int nt = 0; nt < 4; ++nt) {
        int n = nt * 16 + n16;
        b1f[nt] = (n < HD) ? b1[n] : 0.0f;
        b3f[nt] = b3[n];
        w4f[nt] = W4[n];
    }
    float b2f[2] = { b2[n16], b2[16 + n16] };
    const float b4s = b4[0];

    // h state in fp32, C-layout: hC[nt][r] = h[m = quad*4+r][n = nt*16+n16]
    float4v hC[2];
    hC[0] = (float4v){0.0f, 0.0f, 0.0f, 0.0f};
    hC[1] = (float4v){0.0f, 0.0f, 0.0f, 0.0f};

#pragma unroll 1
    for (int t = 0; t < T_STEPS; ++t) {
        // x K-tile fragment (k' = 32..63): quads 0/1 carry x, quads 2/3 are zero pad
        short8 xf;
        if (quad < 2) {
            const float* xr = x + (size_t)(b0 + n16) * (T_STEPS * D_IN) + t * D_IN + quad * 8;
#pragma unroll
            for (int j = 0; j < 8; ++j) xf[j] = f2bf(xr[j]);
        } else {
#pragma unroll
            for (int j = 0; j < 8; ++j) xf[j] = 0;
        }
        // per-row (m = quad*4 + r) scale and y init (replicated across the 16 n-lanes)
        float scl[4], y[4];
#pragma unroll
        for (int r = 0; r < 4; ++r) {
            int b = b0 + quad * 4 + r;
            const float* dtp = dt + (size_t)b * (T_STEPS * 2) + t * 2;
            scl[r] = (dtp[1] - dtp[0]) * DT_SCALERF;
            y[r]   = x[(size_t)b * (T_STEPS * D_IN) + t * D_IN];   // x_i[:,0]
        }

#pragma unroll 1
        for (int e = 0; e < EULER; ++e) {
            // ---- h: fp32 C-layout -> bf16 A-frag via LDS ----
            __syncthreads();   // WAR vs previous iteration's reads
#pragma unroll
            for (int nt = 0; nt < 2; ++nt)
#pragma unroll
                for (int r = 0; r < 4; ++r)
                    h_stage[(quad * 4 + r) * 40 + nt * 16 + n16] = f2bf(hC[nt][r]);
            __syncthreads();
            short8 hf = *(const short8*)&h_stage[n16 * 40 + quad * 8];

            // ---- L1: u1 = [h|x] @ W1^T + b1  (4 N-tiles x 2 K-tiles) ----
            float4v a1[4], a3[4];
#pragma unroll
            for (int nt = 0; nt < 4; ++nt) {
                a1[nt] = (float4v){b1f[nt], b1f[nt], b1f[nt], b1f[nt]};
                a1[nt] = __builtin_amdgcn_mfma_f32_16x16x32_bf16(hf, w1f[nt][0], a1[nt], 0, 0, 0);
                a1[nt] = __builtin_amdgcn_mfma_f32_16x16x32_bf16(xf, w1f[nt][1], a1[nt], 0, 0, 0);
            }
            // ---- L3: u3 = h @ W3^T + b3 (uses pre-update h-frag) ----
#pragma unroll
            for (int nt = 0; nt < 4; ++nt) {
                a3[nt] = (float4v){b3f[nt], b3f[nt], b3f[nt], b3f[nt]};
                a3[nt] = __builtin_amdgcn_mfma_f32_16x16x32_bf16(hf, w3f[nt], a3[nt], 0, 0, 0);
            }

            // ---- tanh(u1) -> LDS -> A-frags for L2 ----
            __syncthreads();
#pragma unroll
            for (int nt = 0; nt < 4; ++nt)
#pragma unroll
                for (int r = 0; r < 4; ++r)
                    a1_stage[(quad * 4 + r) * 72 + nt * 16 + n16] = f2bf(fast_tanh(a1[nt][r]));
            __syncthreads();
            short8 z0 = *(const short8*)&a1_stage[n16 * 72 +  0 + quad * 8];
            short8 z1 = *(const short8*)&a1_stage[n16 * 72 + 32 + quad * 8];

            // ---- L2: u2 = tanh(u1) @ W2^T + b2 ----
            float4v u2[2];
#pragma unroll
            for (int nt = 0; nt < 2; ++nt) {
                u2[nt] = (float4v){b2f[nt], b2f[nt], b2f[nt], b2f[nt]};
                u2[nt] = __builtin_amdgcn_mfma_f32_16x16x32_bf16(z0, w2f[nt][0], u2[nt], 0, 0, 0);
                u2[nt] = __builtin_amdgcn_mfma_f32_16x16x32_bf16(z1, w2f[nt][1], u2[nt], 0, 0, 0);
            }

            // ---- dy path: p[m] = sum_n W4[n]*tanh(u3[m][n]) via VALU + 16-lane reduce ----
            float p[4];
#pragma unroll
            for (int r = 0; r < 4; ++r) {
                float acc = 0.0f;
#pragma unroll
                for (int nt = 0; nt < 4; ++nt)
                    acc += w4f[nt] * fast_tanh(a3[nt][r]);
                p[r] = acc;
            }
#pragma unroll
            for (int m = 1; m < 16; m <<= 1)
#pragma unroll
                for (int r = 0; r < 4; ++r)
                    p[r] += __shfl_xor(p[r], m, 64);

            // ---- state updates (fp32) ----
#pragma unroll
            for (int r = 0; r < 4; ++r) {
                float dy = (p[r] + b4s) * scl[r];
                y[r] += STEPF * dy;
                float s = STEPF * scl[r];
                hC[0][r] += s * fast_tanh(u2[0][r]);
                hC[1][r] += s * fast_tanh(u2[1][r]);
            }
        } // euler

        // ---- store y for this t: one lane column writes the 16 rows ----
        if (n16 == 0) {
#pragma unroll
            for (int r = 0; r < 4; ++r)
                out[(size_t)(b0 + quad * 4 + r) * T_STEPS + t] = y[r];
        }
    } // t
}

extern "C" void kernel_launch(void* const* d_in, const int* in_sizes, int n_in,
                              void* d_out, int out_size, void* d_ws, size_t ws_size,
                              hipStream_t stream) {
    const float* dt = (const float*)d_in[0];
    const float* x  = (const float*)d_in[1];
    const float* W1 = (const float*)d_in[2];
    const float* b1 = (const float*)d_in[3];
    const float* W2 = (const float*)d_in[4];
    const float* b2 = (const float*)d_in[5];
    const float* W3 = (const float*)d_in[6];
    const float* b3 = (const float*)d_in[7];
    const float* W4 = (const float*)d_in[8];
    const float* b4 = (const float*)d_in[9];
    float* out = (float*)d_out;

    const int B = 8192;
    dim3 grid(B / 16), block(64);
    latode_kernel<<<grid, block, 0, stream>>>(dt, x, W1, b1, W2, b2, W3, b3, W4, b4, out);
}

// Round 2
// 1110.153 us; speedup vs baseline: 1.3990x; 1.3990x over previous
//
#include <hip/hip_runtime.h>
#include <stdint.h>

#define T_STEPS 100
#define D_IN 16
#define H_DIM 32
#define HD 50
#define KXH 48
#define EULER 10
#define STEPF 0.1f
#define DT_SCALERF (1.0f/24.0f)

typedef __attribute__((ext_vector_type(8))) short short8;
typedef __attribute__((ext_vector_type(4))) float float4v;
typedef __attribute__((ext_vector_type(2))) uint32_t uint2v;
typedef __attribute__((ext_vector_type(4))) uint32_t uint4v;

__device__ __forceinline__ float fast_tanh(float x) {
    // tanh(x) = 1 - 2/(e^{2x}+1); e^{2x} = exp2(x * 2*log2(e))
    float e = __builtin_amdgcn_exp2f(x * 2.8853900817779268f);
    return 1.0f - 2.0f * __builtin_amdgcn_rcpf(e + 1.0f);
}

__device__ __forceinline__ uint32_t f2bf_u(float f) {
    uint32_t u = __builtin_bit_cast(uint32_t, f);
    return u + 0x7fffu + ((u >> 16) & 1u);   // RNE; bf16 in bits[31:16]
}
__device__ __forceinline__ uint32_t pack2(float lo, float hi) {
    return (f2bf_u(hi) & 0xffff0000u) | (f2bf_u(lo) >> 16);
}
__device__ __forceinline__ short f2bf(float f) { return (short)(f2bf_u(f) >> 16); }

// Transposed formulation: all activations are [feature (M rows)][batch (N cols)].
// Weights are A-operand frags (A[m=lane&15][k=quad*8+j]) -- constant all kernel.
// Activations are B-operand frags (B[n=lane&15][k=quad*8+j]) with n16 = batch.
// C-layout outputs (row = feat = quad*4+r, col = batch = n16) feed the next
// layer via a packed-bf16 LDS round-trip: 2-4 ds_write_b64 + ds_read_b128,
// NO barriers (single-wave block; DS pipe is in-order within a wave).
__global__ __launch_bounds__(64) void latode_kernel(
    const float* __restrict__ dt, const float* __restrict__ x,
    const float* __restrict__ W1, const float* __restrict__ b1,
    const float* __restrict__ W2, const float* __restrict__ b2,
    const float* __restrict__ W3, const float* __restrict__ b3,
    const float* __restrict__ W4, const float* __restrict__ b4,
    float* __restrict__ out)
{
    const int lane = threadIdx.x;     // one wave per block
    const int n16  = lane & 15;       // batch column (activations) / out-feature row (weights)
    const int quad = lane >> 4;
    const int b0   = blockIdx.x * 16;

    // LDS as uint32 (packed bf16 pairs); row strides chosen 16B-aligned, <=2-way banks
    __shared__ __align__(16) uint32_t hbuf[16 * 20];  // [batch][feat-pair 0..15], stride 20 dw = 80 B
    __shared__ __align__(16) uint32_t zbuf[16 * 36];  // [batch][feat-pair 0..31], stride 36 dw = 144 B

    // ---------------- constant weight A-frags (bf16, register-resident) ----------
    // K-space remap for L1: [h(0..31) | x(32..47) | pad(48..63)]
    short8 w1f[4][2];
#pragma unroll
    for (int mt = 0; mt < 4; ++mt) {
        int m = mt * 16 + n16;
#pragma unroll
        for (int kt = 0; kt < 2; ++kt)
#pragma unroll
            for (int j = 0; j < 8; ++j) {
                int kk = kt * 32 + quad * 8 + j;
                float w = 0.0f;
                if (m < HD) {
                    if (kk < 32)      w = W1[m * KXH + 16 + kk];     // h part
                    else if (kk < 48) w = W1[m * KXH + (kk - 32)];   // x part
                }
                w1f[mt][kt][j] = f2bf(w);
            }
    }
    short8 w2f[2][2];
#pragma unroll
    for (int mt = 0; mt < 2; ++mt) {
        int m = mt * 16 + n16;
#pragma unroll
        for (int kt = 0; kt < 2; ++kt)
#pragma unroll
            for (int j = 0; j < 8; ++j) {
                int kk = kt * 32 + quad * 8 + j;
                w2f[mt][kt][j] = f2bf(kk < HD ? W2[m * HD + kk] : 0.0f);
            }
    }
    short8 w3f[4];
#pragma unroll
    for (int mt = 0; mt < 4; ++mt) {
        int m = mt * 16 + n16;
#pragma unroll
        for (int j = 0; j < 8; ++j)
            w3f[mt][j] = f2bf(W3[m * H_DIM + quad * 8 + j]);
    }
    // biases / W4 in C layout: component r -> feature mt*16 + quad*4 + r
    float4v b1v[4], b2v[2], b3v[4], w4v[4];
#pragma unroll
    for (int mt = 0; mt < 4; ++mt)
#pragma unroll
        for (int r = 0; r < 4; ++r) {
            int f = mt * 16 + quad * 4 + r;
            b1v[mt][r] = (f < HD) ? b1[f] : 0.0f;
            b3v[mt][r] = b3[f];
            w4v[mt][r] = W4[f];
        }
#pragma unroll
    for (int mt = 0; mt < 2; ++mt)
#pragma unroll
        for (int r = 0; r < 4; ++r)
            b2v[mt][r] = b2[mt * 16 + quad * 4 + r];
    const float b4s = b4[0];

    // h state fp32, transposed C layout: hC[mt][r] = h[feat mt*16+quad*4+r][batch n16]
    float4v hC[2];
    hC[0] = (float4v){0.f, 0.f, 0.f, 0.f};
    hC[1] = (float4v){0.f, 0.f, 0.f, 0.f};

    // ---- prefetch t=0 inputs ----
    float4 xa = {0,0,0,0}, xb = {0,0,0,0};
    const float* xrow = x + (size_t)(b0 + n16) * (T_STEPS * D_IN);
    const float* drow = dt + (size_t)(b0 + n16) * (T_STEPS * 2);
    if (quad < 2) {
        xa = *(const float4*)(xrow + quad * 8);
        xb = *(const float4*)(xrow + quad * 8 + 4);
    }
    float2 dtv = *(const float2*)(drow);

#pragma unroll 1
    for (int t = 0; t < T_STEPS; ++t) {
        // build x B-frag (k' = 32..63: quads 0/1 carry x, 2/3 zero)
        short8 xB;
        if (quad < 2) {
            uint4v xp;
            xp[0] = pack2(xa.x, xa.y); xp[1] = pack2(xa.z, xa.w);
            xp[2] = pack2(xb.x, xb.y); xp[3] = pack2(xb.z, xb.w);
            xB = __builtin_bit_cast(short8, xp);
        } else {
            xB = (short8){0,0,0,0,0,0,0,0};
        }
        const float scl = (dtv.y - dtv.x) * DT_SCALERF;
        const float s10 = STEPF * scl;
        // y0 = x_t[batch][0] = xa.x of the quad-0 lane with this n16
        float y = __shfl(xa.x, n16, 64);

        // prefetch t+1 (covered by the 10-iteration Euler loop)
        {
            int tn = (t + 1 < T_STEPS) ? t + 1 : (T_STEPS - 1);
            if (quad < 2) {
                xa = *(const float4*)(xrow + tn * D_IN + quad * 8);
                xb = *(const float4*)(xrow + tn * D_IN + quad * 8 + 4);
            }
            dtv = *(const float2*)(drow + tn * 2);
        }

#pragma unroll 1
        for (int e = 0; e < EULER; ++e) {
            // ---- h: fp32 C-layout -> packed bf16 -> LDS -> B-frag ----
            *(uint2v*)&hbuf[n16 * 20 + 0 * 8 + quad * 2] =
                (uint2v){pack2(hC[0][0], hC[0][1]), pack2(hC[0][2], hC[0][3])};
            *(uint2v*)&hbuf[n16 * 20 + 1 * 8 + quad * 2] =
                (uint2v){pack2(hC[1][0], hC[1][1]), pack2(hC[1][2], hC[1][3])};
            short8 hB = __builtin_bit_cast(short8, *(const uint4v*)&hbuf[n16 * 20 + quad * 4]);

            // ---- L1: u1^T = W1 . [h|x]^T + b1 (4 M-tiles x 2 K-tiles) ----
            float4v a1[4], a3[4];
#pragma unroll
            for (int mt = 0; mt < 4; ++mt) {
                a1[mt] = b1v[mt];
                a1[mt] = __builtin_amdgcn_mfma_f32_16x16x32_bf16(w1f[mt][0], hB, a1[mt], 0, 0, 0);
                a1[mt] = __builtin_amdgcn_mfma_f32_16x16x32_bf16(w1f[mt][1], xB, a1[mt], 0, 0, 0);
            }
            // ---- L3: u3^T = W3 . h^T + b3 (pre-update h) ----
#pragma unroll
            for (int mt = 0; mt < 4; ++mt) {
                a3[mt] = b3v[mt];
                a3[mt] = __builtin_amdgcn_mfma_f32_16x16x32_bf16(w3f[mt], hB, a3[mt], 0, 0, 0);
            }

            // ---- z = tanh(u1): pack -> LDS ----
#pragma unroll
            for (int mt = 0; mt < 4; ++mt) {
                float z0 = fast_tanh(a1[mt][0]), z1 = fast_tanh(a1[mt][1]);
                float z2 = fast_tanh(a1[mt][2]), z3 = fast_tanh(a1[mt][3]);
                *(uint2v*)&zbuf[n16 * 36 + mt * 8 + quad * 2] =
                    (uint2v){pack2(z0, z1), pack2(z2, z3)};
            }

            // ---- dy path (fills DS latency): p = sum_f W4[f]*tanh(u3[f][b]) ----
            float pacc = 0.0f;
#pragma unroll
            for (int mt = 0; mt < 4; ++mt) {
                pacc += w4v[mt][0] * fast_tanh(a3[mt][0]);
                pacc += w4v[mt][1] * fast_tanh(a3[mt][1]);
                pacc += w4v[mt][2] * fast_tanh(a3[mt][2]);
                pacc += w4v[mt][3] * fast_tanh(a3[mt][3]);
            }
            pacc += __shfl_xor(pacc, 16, 64);
            pacc += __shfl_xor(pacc, 32, 64);
            y += STEPF * ((pacc + b4s) * scl);

            // ---- L2: u2^T = W2 . z + b2 ----
            short8 zB0 = __builtin_bit_cast(short8, *(const uint4v*)&zbuf[n16 * 36 + quad * 4]);
            short8 zB1 = __builtin_bit_cast(short8, *(const uint4v*)&zbuf[n16 * 36 + 16 + quad * 4]);
            float4v u2[2];
#pragma unroll
            for (int mt = 0; mt < 2; ++mt) {
                u2[mt] = b2v[mt];
                u2[mt] = __builtin_amdgcn_mfma_f32_16x16x32_bf16(w2f[mt][0], zB0, u2[mt], 0, 0, 0);
                u2[mt] = __builtin_amdgcn_mfma_f32_16x16x32_bf16(w2f[mt][1], zB1, u2[mt], 0, 0, 0);
            }
            // ---- h += STEP*scale*tanh(u2) ----
#pragma unroll
            for (int mt = 0; mt < 2; ++mt) {
                hC[mt][0] += s10 * fast_tanh(u2[mt][0]);
                hC[mt][1] += s10 * fast_tanh(u2[mt][1]);
                hC[mt][2] += s10 * fast_tanh(u2[mt][2]);
                hC[mt][3] += s10 * fast_tanh(u2[mt][3]);
            }
        } // euler

        if (quad == 0)
            out[(size_t)(b0 + n16) * T_STEPS + t] = y;
    } // t
}

extern "C" void kernel_launch(void* const* d_in, const int* in_sizes, int n_in,
                              void* d_out, int out_size, void* d_ws, size_t ws_size,
                              hipStream_t stream) {
    const float* dt = (const float*)d_in[0];
    const float* x  = (const float*)d_in[1];
    const float* W1 = (const float*)d_in[2];
    const float* b1 = (const float*)d_in[3];
    const float* W2 = (const float*)d_in[4];
    const float* b2 = (const float*)d_in[5];
    const float* W3 = (const float*)d_in[6];
    const float* b3 = (const float*)d_in[7];
    const float* W4 = (const float*)d_in[8];
    const float* b4 = (const float*)d_in[9];
    float* out = (float*)d_out;

    const int B = 8192;
    dim3 grid(B / 16), block(64);
    latode_kernel<<<grid, block, 0, stream>>>(dt, x, W1, b1, W2, b2, W3, b3, W4, b4, out);
}

// Round 3
// 801.399 us; speedup vs baseline: 1.9380x; 1.3853x over previous
//
#include <hip/hip_runtime.h>
#include <stdint.h>

#define T_STEPS 100
#define D_IN 16
#define H_DIM 32
#define HD 50
#define KXH 48
#define EULER 10
#define STEPF 0.1f
#define DT_SCALERF (1.0f/24.0f)

typedef __attribute__((ext_vector_type(8))) short short8;
typedef __attribute__((ext_vector_type(4))) float float4v;
typedef __attribute__((ext_vector_type(2))) uint32_t uint2v;
typedef __attribute__((ext_vector_type(4))) uint32_t uint4v;

__device__ __forceinline__ float fast_tanh(float x) {
    float e = __builtin_amdgcn_exp2f(x * 2.8853900817779268f);
    return 1.0f - 2.0f * __builtin_amdgcn_rcpf(e + 1.0f);
}
__device__ __forceinline__ uint32_t f2bf_u(float f) {
    uint32_t u = __builtin_bit_cast(uint32_t, f);
    return u + 0x7fffu + ((u >> 16) & 1u);   // RNE; bf16 in bits[31:16]
}
__device__ __forceinline__ uint32_t pack2(float lo, float hi) {
    return (f2bf_u(hi) & 0xffff0000u) | (f2bf_u(lo) >> 16);
}
__device__ __forceinline__ short f2bf(float f) { return (short)(f2bf_u(f) >> 16); }

// 4-wave cooperative block, 16 batch/block. Transposed formulation (weights =
// A-frags, activations = B-frags with batch in lane&15). Wave w owns feature
// tile mt=w of L1/L3; waves 0,1 own u2 tiles + h halves; wave 3 owns dy/y.
// Cross-wave exchange uses the h/z LDS transposes that exist anyway.
__global__ __launch_bounds__(256) void latode_kernel(
    const float* __restrict__ dt, const float* __restrict__ x,
    const float* __restrict__ W1, const float* __restrict__ b1,
    const float* __restrict__ W2, const float* __restrict__ b2,
    const float* __restrict__ W3, const float* __restrict__ b3,
    const float* __restrict__ W4, const float* __restrict__ b4,
    float* __restrict__ out)
{
    const int tid  = threadIdx.x;
    const int wave = tid >> 6;
    const int lane = tid & 63;
    const int n16  = lane & 15;       // batch column / weight out-feature row
    const int quad = lane >> 4;
    const int b0   = blockIdx.x * 16;
    const int mt   = wave;            // this wave's feature tile for L1/L3

    __shared__ __align__(16) uint32_t hbuf[16 * 20];  // [batch][feat-pair], stride 20 dw
    __shared__ __align__(16) uint32_t zbuf[16 * 36];  // [batch][feat-pair], stride 36 dw
    __shared__ float pbuf[64];                        // per-wave dy partials [wave][batch]

    // ---- constant weight A-frags for this wave ----
    // L1 K-remap: [h(0..31) | x(32..47) | pad(48..63)]
    short8 w1f[2];
    {
        int m = mt * 16 + n16;
#pragma unroll
        for (int kt = 0; kt < 2; ++kt)
#pragma unroll
            for (int j = 0; j < 8; ++j) {
                int kk = kt * 32 + quad * 8 + j;
                float w = 0.0f;
                if (m < HD) {
                    if (kk < 32)      w = W1[m * KXH + 16 + kk];
                    else if (kk < 48) w = W1[m * KXH + (kk - 32)];
                }
                w1f[kt][j] = f2bf(w);
            }
    }
    short8 w3f;
    {
        int m = mt * 16 + n16;
#pragma unroll
        for (int j = 0; j < 8; ++j)
            w3f[j] = f2bf(W3[m * H_DIM + quad * 8 + j]);
    }
    float4v b1v, b3v, w4v;
#pragma unroll
    for (int r = 0; r < 4; ++r) {
        int f = mt * 16 + quad * 4 + r;
        b1v[r] = (f < HD) ? b1[f] : 0.0f;
        b3v[r] = b3[f];
        w4v[r] = W4[f];
    }
    short8 w2f[2];
    float4v b2v;
    if (wave < 2) {
        int m = wave * 16 + n16;
#pragma unroll
        for (int kt = 0; kt < 2; ++kt)
#pragma unroll
            for (int j = 0; j < 8; ++j) {
                int kk = kt * 32 + quad * 8 + j;
                w2f[kt][j] = f2bf(kk < HD ? W2[m * HD + kk] : 0.0f);
            }
#pragma unroll
        for (int r = 0; r < 4; ++r)
            b2v[r] = b2[wave * 16 + quad * 4 + r];
    }
    const float b4s = b4[0];

    // h half owned by waves 0,1 (feats wave*16 + quad*4 + r, batch n16)
    float4v hC = (float4v){0.f, 0.f, 0.f, 0.f};

    // init hbuf with zeros
    if (wave < 2)
        *(uint2v*)&hbuf[n16 * 20 + wave * 8 + quad * 2] = (uint2v){0u, 0u};
    __syncthreads();

    // per-wave input prefetch (t=0)
    float4 xa = {0,0,0,0}, xb = {0,0,0,0};
    const float* xrow = x + (size_t)(b0 + n16) * (T_STEPS * D_IN);
    const float* drow = dt + (size_t)(b0 + n16) * (T_STEPS * 2);
    if (quad < 2) {
        xa = *(const float4*)(xrow + quad * 8);
        xb = *(const float4*)(xrow + quad * 8 + 4);
    }
    float2 dtv = *(const float2*)(drow);

#pragma unroll 1
    for (int t = 0; t < T_STEPS; ++t) {
        short8 xB;
        if (quad < 2) {
            uint4v xp;
            xp[0] = pack2(xa.x, xa.y); xp[1] = pack2(xa.z, xa.w);
            xp[2] = pack2(xb.x, xb.y); xp[3] = pack2(xb.z, xb.w);
            xB = __builtin_bit_cast(short8, xp);
        } else {
            xB = (short8){0,0,0,0,0,0,0,0};
        }
        const float scl = (dtv.y - dtv.x) * DT_SCALERF;
        const float s10 = STEPF * scl;
        float y = __shfl(xa.x, n16, 64);   // x_t[batch n16][0] (valid everywhere; used by wave 3)

        { // prefetch t+1
            int tn = (t + 1 < T_STEPS) ? t + 1 : (T_STEPS - 1);
            if (quad < 2) {
                xa = *(const float4*)(xrow + tn * D_IN + quad * 8);
                xb = *(const float4*)(xrow + tn * D_IN + quad * 8 + 4);
            }
            dtv = *(const float2*)(drow + tn * 2);
        }

#pragma unroll 1
        for (int e = 0; e < EULER; ++e) {
            // ---- phase A (all waves): read h, do L1 + L3 for tile mt ----
            short8 hB = __builtin_bit_cast(short8, *(const uint4v*)&hbuf[n16 * 20 + quad * 4]);

            float4v a1 = b1v, a3 = b3v;
            a1 = __builtin_amdgcn_mfma_f32_16x16x32_bf16(w1f[0], hB, a1, 0, 0, 0);
            a1 = __builtin_amdgcn_mfma_f32_16x16x32_bf16(w1f[1], xB, a1, 0, 0, 0);
            a3 = __builtin_amdgcn_mfma_f32_16x16x32_bf16(w3f, hB, a3, 0, 0, 0);

            // z = tanh(u1) -> packed -> zbuf (this wave's quarter)
            {
                float z0 = fast_tanh(a1[0]), z1 = fast_tanh(a1[1]);
                float z2 = fast_tanh(a1[2]), z3 = fast_tanh(a1[3]);
                *(uint2v*)&zbuf[n16 * 36 + mt * 8 + quad * 2] =
                    (uint2v){pack2(z0, z1), pack2(z2, z3)};
            }
            // dy partial: sum over this wave's 16 features
            {
                float pacc = w4v[0] * fast_tanh(a3[0]) + w4v[1] * fast_tanh(a3[1])
                           + w4v[2] * fast_tanh(a3[2]) + w4v[3] * fast_tanh(a3[3]);
                pacc += __shfl_xor(pacc, 16, 64);
                pacc += __shfl_xor(pacc, 32, 64);
                if (lane < 16) pbuf[wave * 16 + n16] = pacc;
            }
            __syncthreads();   // barrier 1: z + p visible; h reads done (WAR)

            // ---- phase B ----
            if (wave < 2) {
                short8 zB0 = __builtin_bit_cast(short8, *(const uint4v*)&zbuf[n16 * 36 + quad * 4]);
                short8 zB1 = __builtin_bit_cast(short8, *(const uint4v*)&zbuf[n16 * 36 + 16 + quad * 4]);
                float4v u2 = b2v;
                u2 = __builtin_amdgcn_mfma_f32_16x16x32_bf16(w2f[0], zB0, u2, 0, 0, 0);
                u2 = __builtin_amdgcn_mfma_f32_16x16x32_bf16(w2f[1], zB1, u2, 0, 0, 0);
                hC[0] += s10 * fast_tanh(u2[0]);
                hC[1] += s10 * fast_tanh(u2[1]);
                hC[2] += s10 * fast_tanh(u2[2]);
                hC[3] += s10 * fast_tanh(u2[3]);
                *(uint2v*)&hbuf[n16 * 20 + wave * 8 + quad * 2] =
                    (uint2v){pack2(hC[0], hC[1]), pack2(hC[2], hC[3])};
            } else if (wave == 3) {
                float ptot = pbuf[n16] + pbuf[16 + n16] + pbuf[32 + n16] + pbuf[48 + n16];
                y += STEPF * ((ptot + b4s) * scl);
            }
            __syncthreads();   // barrier 2: h visible for next step; z/p WAR
        } // euler

        if (wave == 3 && quad == 0)
            out[(size_t)(b0 + n16) * T_STEPS + t] = y;
    } // t
}

extern "C" void kernel_launch(void* const* d_in, const int* in_sizes, int n_in,
                              void* d_out, int out_size, void* d_ws, size_t ws_size,
                              hipStream_t stream) {
    const float* dt = (const float*)d_in[0];
    const float* x  = (const float*)d_in[1];
    const float* W1 = (const float*)d_in[2];
    const float* b1 = (const float*)d_in[3];
    const float* W2 = (const float*)d_in[4];
    const float* b2 = (const float*)d_in[5];
    const float* W3 = (const float*)d_in[6];
    const float* b3 = (const float*)d_in[7];
    const float* W4 = (const float*)d_in[8];
    const float* b4 = (const float*)d_in[9];
    float* out = (float*)d_out;

    const int B = 8192;
    dim3 grid(B / 16), block(256);
    latode_kernel<<<grid, block, 0, stream>>>(dt, x, W1, b1, W2, b2, W3, b3, W4, b4, out);
}

// Round 4
// 761.930 us; speedup vs baseline: 2.0384x; 1.0518x over previous
//
#include <hip/hip_runtime.h>
#include <stdint.h>

#define T_STEPS 100
#define D_IN 16
#define H_DIM 32
#define HD 50
#define KXH 48
#define EULER 10
#define STEPF 0.1f
#define DT_SCALERF (1.0f/24.0f)
#define TANH_SCALE 2.8853900817779268f   // 2*log2(e), folded into W1/W3/W2+biases

typedef __attribute__((ext_vector_type(8))) short short8;
typedef __attribute__((ext_vector_type(4))) float float4v;
typedef __attribute__((ext_vector_type(2))) uint32_t uint2v;
typedef __attribute__((ext_vector_type(4))) uint32_t uint4v;

// input already scaled by 2*log2(e): tanh(u) = 1 - 2/(exp2(us)+1)
__device__ __forceinline__ float tanh_pre(float us) {
    float e = __builtin_amdgcn_exp2f(us);
    return 1.0f - 2.0f * __builtin_amdgcn_rcpf(e + 1.0f);
}
__device__ __forceinline__ uint32_t f2bf_u(float f) {
    uint32_t u = __builtin_bit_cast(uint32_t, f);
    return u + 0x7fffu + ((u >> 16) & 1u);   // RNE; bf16 in bits[31:16]
}
__device__ __forceinline__ uint32_t pack2(float lo, float hi) {
    return (f2bf_u(hi) & 0xffff0000u) | (f2bf_u(lo) >> 16);
}
__device__ __forceinline__ short f2bf(float f) { return (short)(f2bf_u(f) >> 16); }

// 8-wave cooperative block, 16 batch/block, transposed formulation
// (weights = A-frags, activations = B-frags, batch in lane&15).
// Phase A: waves 0-3 own u1 tile w (2 MFMA + z-tanh -> zbuf);
//          waves 4-7 own u3 tile w-4 (1 MFMA + dy-tanh -> pbuf partial).
// Phase B: wave 6/7 own u2 tile 0/1 + fp32 h half (-> hbuf);
//          wave 4 accumulates lazy-y partial sums.
// 2 barriers per Euler step (structural RAW both directions).
__global__ __launch_bounds__(512, 4) void latode_kernel(
    const float* __restrict__ dt, const float* __restrict__ x,
    const float* __restrict__ W1, const float* __restrict__ b1,
    const float* __restrict__ W2, const float* __restrict__ b2,
    const float* __restrict__ W3, const float* __restrict__ b3,
    const float* __restrict__ W4, const float* __restrict__ b4,
    float* __restrict__ out)
{
    const int tid  = threadIdx.x;
    const int wave = tid >> 6;
    const int lane = tid & 63;
    const int n16  = lane & 15;       // batch column
    const int quad = lane >> 4;
    const int b0   = blockIdx.x * 16;
    const int mt   = wave & 3;        // this wave's feature tile
    const bool is_u1 = (wave < 4);

    __shared__ __align__(16) uint32_t hbuf[16 * 20];  // [batch][feat-pair 0..15], stride 20 dw
    __shared__ __align__(16) uint32_t zbuf[16 * 36];  // [batch][feat-pair 0..31], stride 36 dw
    __shared__ float pbuf[64];                        // dy partials [u3-tile][batch]

    // zero-init LDS (re-poisoned 0xAA before every launch)
    for (int i = tid; i < 16 * 20; i += 512) hbuf[i] = 0;
    for (int i = tid; i < 16 * 36; i += 512) zbuf[i] = 0;

    // ---- per-wave constant weight A-frags (bf16, prescaled by 2*log2e) ----
    short8 wA[2];           // u1: 2 K-tiles; u3: wA[0] only
    float4v bA, w4v;
    if (is_u1) {
        int m = mt * 16 + n16;
#pragma unroll
        for (int kt = 0; kt < 2; ++kt)
#pragma unroll
            for (int j = 0; j < 8; ++j) {
                int kk = kt * 32 + quad * 8 + j;   // K remap: [h(0..31)|x(32..47)|pad]
                float w = 0.0f;
                if (m < HD) {
                    if (kk < 32)      w = W1[m * KXH + 16 + kk];
                    else if (kk < 48) w = W1[m * KXH + (kk - 32)];
                }
                wA[kt][j] = f2bf(w * TANH_SCALE);
            }
#pragma unroll
        for (int r = 0; r < 4; ++r) {
            int f = mt * 16 + quad * 4 + r;
            bA[r] = (f < HD) ? b1[f] * TANH_SCALE : 0.0f;
        }
    } else {
        int m = mt * 16 + n16;
#pragma unroll
        for (int j = 0; j < 8; ++j)
            wA[0][j] = f2bf(W3[m * H_DIM + quad * 8 + j] * TANH_SCALE);
#pragma unroll
        for (int r = 0; r < 4; ++r) {
            int f = mt * 16 + quad * 4 + r;
            bA[r] = b3[f] * TANH_SCALE;
            w4v[r] = W4[f];
        }
    }
    short8 w2f[2];
    float4v b2v;
    if (wave >= 6) {
        int m = (wave - 6) * 16 + n16;
#pragma unroll
        for (int kt = 0; kt < 2; ++kt)
#pragma unroll
            for (int j = 0; j < 8; ++j) {
                int kk = kt * 32 + quad * 8 + j;
                w2f[kt][j] = f2bf(kk < HD ? W2[m * HD + kk] * TANH_SCALE : 0.0f);
            }
#pragma unroll
        for (int r = 0; r < 4; ++r)
            b2v[r] = b2[(wave - 6) * 16 + quad * 4 + r] * TANH_SCALE;
    }
    const float b4s = b4[0];

    // fp32 h half owned by waves 6,7
    float4v hC = (float4v){0.f, 0.f, 0.f, 0.f};

    // per-wave input prefetch (t=0)
    const float* xrow = x + (size_t)(b0 + n16) * (T_STEPS * D_IN);
    const float* drow = dt + (size_t)(b0 + n16) * (T_STEPS * 2);
    float4 xa = {0,0,0,0}, xb = {0,0,0,0};
    float2 dtv = {0.f, 0.f};
    float y0 = 0.f;
    if (is_u1 && quad < 2) {
        xa = *(const float4*)(xrow + quad * 8);
        xb = *(const float4*)(xrow + quad * 8 + 4);
    }
    if (wave == 4 || wave >= 6) dtv = *(const float2*)(drow);
    if (wave == 4) y0 = xrow[0];

    __syncthreads();   // LDS zero-init visible

#pragma unroll 1
    for (int t = 0; t < T_STEPS; ++t) {
        short8 xB = (short8){0,0,0,0,0,0,0,0};
        if (is_u1 && quad < 2) {
            uint4v xp;
            xp[0] = pack2(xa.x, xa.y); xp[1] = pack2(xa.z, xa.w);
            xp[2] = pack2(xb.x, xb.y); xp[3] = pack2(xb.z, xb.w);
            xB = __builtin_bit_cast(short8, xp);
        }
        const float scl = (dtv.y - dtv.x) * DT_SCALERF;   // waves 4,6,7
        const float s10 = STEPF * scl;
        const float y0c = y0;                              // wave 4: y0 for this t
        float psum = 0.f;

        { // prefetch t+1
            int tn = (t + 1 < T_STEPS) ? t + 1 : (T_STEPS - 1);
            if (is_u1 && quad < 2) {
                xa = *(const float4*)(xrow + tn * D_IN + quad * 8);
                xb = *(const float4*)(xrow + tn * D_IN + quad * 8 + 4);
            }
            if (wave == 4 || wave >= 6) dtv = *(const float2*)(drow + tn * 2);
            if (wave == 4) y0 = xrow[tn * D_IN];
        }

#pragma unroll 1
        for (int e = 0; e < EULER; ++e) {
            short8 hB = __builtin_bit_cast(short8, *(const uint4v*)&hbuf[n16 * 20 + quad * 4]);

            if (is_u1) {
                float4v a = bA;
                a = __builtin_amdgcn_mfma_f32_16x16x32_bf16(wA[0], hB, a, 0, 0, 0);
                a = __builtin_amdgcn_mfma_f32_16x16x32_bf16(wA[1], xB, a, 0, 0, 0);
                if (wave < 3) {
                    float z0 = tanh_pre(a[0]), z1 = tanh_pre(a[1]);
                    float z2 = tanh_pre(a[2]), z3 = tanh_pre(a[3]);
                    *(uint2v*)&zbuf[n16 * 36 + mt * 8 + quad * 2] =
                        (uint2v){pack2(z0, z1), pack2(z2, z3)};
                } else {
                    // tile 3: only feats 48,49 real (quad 0, regs 0,1); rest stays 0
                    float z0 = tanh_pre(a[0]), z1 = tanh_pre(a[1]);
                    if (quad == 0) zbuf[n16 * 36 + 24] = pack2(z0, z1);
                }
            } else {
                float4v a = bA;
                a = __builtin_amdgcn_mfma_f32_16x16x32_bf16(wA[0], hB, a, 0, 0, 0);
                float pacc = w4v[0] * tanh_pre(a[0]) + w4v[1] * tanh_pre(a[1])
                           + w4v[2] * tanh_pre(a[2]) + w4v[3] * tanh_pre(a[3]);
                pacc += __shfl_xor(pacc, 16, 64);
                pacc += __shfl_xor(pacc, 32, 64);
                if (lane < 16) pbuf[mt * 16 + n16] = pacc;
            }
            __syncthreads();   // z,p visible; hbuf reads done (WAR for B's h write)

            if (wave >= 6) {
                short8 zB0 = __builtin_bit_cast(short8, *(const uint4v*)&zbuf[n16 * 36 + quad * 4]);
                short8 zB1 = __builtin_bit_cast(short8, *(const uint4v*)&zbuf[n16 * 36 + 16 + quad * 4]);
                float4v u2 = b2v;
                u2 = __builtin_amdgcn_mfma_f32_16x16x32_bf16(w2f[0], zB0, u2, 0, 0, 0);
                u2 = __builtin_amdgcn_mfma_f32_16x16x32_bf16(w2f[1], zB1, u2, 0, 0, 0);
                hC[0] += s10 * tanh_pre(u2[0]);
                hC[1] += s10 * tanh_pre(u2[1]);
                hC[2] += s10 * tanh_pre(u2[2]);
                hC[3] += s10 * tanh_pre(u2[3]);
                *(uint2v*)&hbuf[n16 * 20 + (wave - 6) * 8 + quad * 2] =
                    (uint2v){pack2(hC[0], hC[1]), pack2(hC[2], hC[3])};
            } else if (wave == 4) {
                psum += pbuf[n16] + pbuf[16 + n16] + pbuf[32 + n16] + pbuf[48 + n16];
            }
            __syncthreads();   // h visible; zbuf/pbuf WAR cleared
        } // euler

        if (wave == 4 && quad == 0) {
            float y = y0c + STEPF * scl * (psum + (float)EULER * b4s);
            out[(size_t)(b0 + n16) * T_STEPS + t] = y;
        }
    } // t
}

extern "C" void kernel_launch(void* const* d_in, const int* in_sizes, int n_in,
                              void* d_out, int out_size, void* d_ws, size_t ws_size,
                              hipStream_t stream) {
    const float* dt = (const float*)d_in[0];
    const float* x  = (const float*)d_in[1];
    const float* W1 = (const float*)d_in[2];
    const float* b1 = (const float*)d_in[3];
    const float* W2 = (const float*)d_in[4];
    const float* b2 = (const float*)d_in[5];
    const float* W3 = (const float*)d_in[6];
    const float* b3 = (const float*)d_in[7];
    const float* W4 = (const float*)d_in[8];
    const float* b4 = (const float*)d_in[9];
    float* out = (float*)d_out;

    const int B = 8192;
    dim3 grid(B / 16), block(512);
    latode_kernel<<<grid, block, 0, stream>>>(dt, x, W1, b1, W2, b2, W3, b3, W4, b4, out);
}